// Round 2
// baseline (1886.182 us; speedup 1.0000x reference)
//
#include <hip/hip_runtime.h>
#include <hip/hip_bf16.h>

typedef unsigned short u16;
typedef unsigned int u32;

__device__ __forceinline__ float b2f(u16 u) {
    return __uint_as_float(((u32)u) << 16);
}
__device__ __forceinline__ u16 f2b(float f) {
    u32 u = __float_as_uint(f);
    u32 r = (u + 0x7FFFu + ((u >> 16) & 1u)) >> 16;
    return (u16)r;
}

#define NEGV -1e9f

// ---------------------------------------------------------------------------
// Tiled GEMM: C = A(MxK) @ W(KxN) + bias(N).  W,bias fp32.
// AF32: 1 -> A fp32, 0 -> A bf16 (u16)
// OHS : 1 -> write bf16 head-split [b][h][l][d], 0 -> write fp32 row-major
// block: 256 threads, 64x64 tile, each thread 4x4, K-step 16.
// ---------------------------------------------------------------------------
template<int AF32, int OHS>
__global__ __launch_bounds__(256) void gemm_bias(
    const void* __restrict__ Av, const float* __restrict__ W,
    const float* __restrict__ bias, u16* __restrict__ outHS,
    float* __restrict__ outF, int M, int N, int K)
{
    __shared__ float As[64][17];
    __shared__ float Bs[16][65];
    const int t  = threadIdx.x;
    const int tx = t & 15, ty = t >> 4;
    const int bm = blockIdx.y << 6, bn = blockIdx.x << 6;
    const int ar = t >> 2, ac = (t & 3) << 2;     // A tile: 64 rows x 16 cols
    const int wr = t >> 4, wc = (t & 15) << 2;    // W tile: 16 rows x 64 cols
    float c[4][4] = {{0.f,0.f,0.f,0.f},{0.f,0.f,0.f,0.f},{0.f,0.f,0.f,0.f},{0.f,0.f,0.f,0.f}};

    for (int k0 = 0; k0 < K; k0 += 16) {
        if (AF32) {
            const float* A = (const float*)Av;
            float4 av = *reinterpret_cast<const float4*>(A + (size_t)(bm + ar) * K + k0 + ac);
            As[ar][ac + 0] = av.x; As[ar][ac + 1] = av.y;
            As[ar][ac + 2] = av.z; As[ar][ac + 3] = av.w;
        } else {
            const u16* A = (const u16*)Av;
            ushort4 av = *reinterpret_cast<const ushort4*>(A + (size_t)(bm + ar) * K + k0 + ac);
            As[ar][ac + 0] = b2f(av.x); As[ar][ac + 1] = b2f(av.y);
            As[ar][ac + 2] = b2f(av.z); As[ar][ac + 3] = b2f(av.w);
        }
        {
            float4 wv = *reinterpret_cast<const float4*>(W + (size_t)(k0 + wr) * N + bn + wc);
            Bs[wr][wc + 0] = wv.x; Bs[wr][wc + 1] = wv.y;
            Bs[wr][wc + 2] = wv.z; Bs[wr][wc + 3] = wv.w;
        }
        __syncthreads();
        #pragma unroll
        for (int kk = 0; kk < 16; ++kk) {
            float a0 = As[(ty << 2) + 0][kk];
            float a1 = As[(ty << 2) + 1][kk];
            float a2 = As[(ty << 2) + 2][kk];
            float a3 = As[(ty << 2) + 3][kk];
            float b0 = Bs[kk][(tx << 2) + 0];
            float b1 = Bs[kk][(tx << 2) + 1];
            float b2 = Bs[kk][(tx << 2) + 2];
            float b3 = Bs[kk][(tx << 2) + 3];
            c[0][0] += a0 * b0; c[0][1] += a0 * b1; c[0][2] += a0 * b2; c[0][3] += a0 * b3;
            c[1][0] += a1 * b0; c[1][1] += a1 * b1; c[1][2] += a1 * b2; c[1][3] += a1 * b3;
            c[2][0] += a2 * b0; c[2][1] += a2 * b1; c[2][2] += a2 * b2; c[2][3] += a2 * b3;
            c[3][0] += a3 * b0; c[3][1] += a3 * b1; c[3][2] += a3 * b2; c[3][3] += a3 * b3;
        }
        __syncthreads();
    }

    #pragma unroll
    for (int i = 0; i < 4; ++i) {
        int row = bm + (ty << 2) + i;
        #pragma unroll
        for (int j = 0; j < 4; ++j) {
            int col = bn + (tx << 2) + j;
            float val = c[i][j] + bias[col];
            if (OHS) {
                int bb = row >> 10, l = row & 1023, hh = col >> 6, dd = col & 63;
                outHS[((((size_t)bb * 12 + hh) << 10) + l) * 64 + dd] = f2b(val);
            } else {
                outF[(size_t)row * N + col] = val;
            }
        }
    }
}

// ---------------------------------------------------------------------------
// Attention: 1 block = (b, h, tile of 8 q-rows). 256 threads.
// Reproduces reference fp32 masking arithmetic exactly:
//   s = (q.k)*scale; if padded -> -1e9 (replace); fw = s + (k<q ? -1e9 : 0);
//   softmax(max-subtract) over ALL 1024 logits; w = a_fw + a_bw; out = w @ V.
// ---------------------------------------------------------------------------
__global__ __launch_bounds__(256) void attn_kernel(
    const u16* __restrict__ Qf, const u16* __restrict__ Kf,
    const u16* __restrict__ Vf, const int* __restrict__ mask,
    u16* __restrict__ att)
{
    __shared__ float qs[8][64];
    __shared__ u16 kv[256][66];     // padded row stride: conflict-free
    __shared__ float sc[8][1024];

    const int t  = threadIdx.x;
    const int blk = blockIdx.x;
    const int qt = blk & 127;        // 1024/8 = 128 q-tiles
    const int bh = blk >> 7;         // 0..95
    const int b  = bh / 12;
    const int h  = bh - b * 12;

    const u16* Kh = Kf + (size_t)bh * (1024 * 64);
    const u16* Vh = Vf + (size_t)bh * (1024 * 64);
    const u16* Qh = Qf + (size_t)bh * (1024 * 64) + (size_t)qt * 8 * 64;

    for (int idx = t; idx < 8 * 64; idx += 256)
        qs[idx >> 6][idx & 63] = b2f(Qh[idx]);

    // ---- scores ----
    for (int kt = 0; kt < 4; ++kt) {
        __syncthreads();
        {
            const uint4* src = reinterpret_cast<const uint4*>(Kh + (size_t)(kt * 256 + t) * 64);
            u32* dst = reinterpret_cast<u32*>(&kv[t][0]);
            #pragma unroll
            for (int i = 0; i < 8; ++i) {
                uint4 vv = src[i];
                dst[i * 4 + 0] = vv.x; dst[i * 4 + 1] = vv.y;
                dst[i * 4 + 2] = vv.z; dst[i * 4 + 3] = vv.w;
            }
        }
        __syncthreads();
        const int kg = (kt << 8) + t;
        const int pm = mask[b * 1024 + kg];
        float kr[64];
        #pragma unroll
        for (int d = 0; d < 64; ++d) kr[d] = b2f(kv[t][d]);
        for (int r = 0; r < 8; ++r) {
            float acc = 0.f;
            #pragma unroll
            for (int d = 0; d < 64; ++d) acc += qs[r][d] * kr[d];
            float s = acc * 0.125f;
            sc[r][kg] = pm ? NEGV : s;
        }
    }
    __syncthreads();

    // ---- dual softmax (row g handled by 32-lane group) ----
    {
        const int g    = t >> 5;
        const int lane = t & 31;
        const int qg   = (qt << 3) + g;
        float sv[32];
        float mfw = -3.0e38f, mbw = -3.0e38f;
        #pragma unroll
        for (int j = 0; j < 32; ++j) {
            int k = lane + (j << 5);
            float s = sc[g][k];
            sv[j] = s;
            float fw = s + (k < qg ? NEGV : 0.f);
            float bw = s + (k > qg ? NEGV : 0.f);
            mfw = fmaxf(mfw, fw);
            mbw = fmaxf(mbw, bw);
        }
        #pragma unroll
        for (int m = 16; m >= 1; m >>= 1) {
            mfw = fmaxf(mfw, __shfl_xor(mfw, m));
            mbw = fmaxf(mbw, __shfl_xor(mbw, m));
        }
        float sfw = 0.f, sbw = 0.f;
        #pragma unroll
        for (int j = 0; j < 32; ++j) {
            int k = lane + (j << 5);
            float s = sv[j];
            float fw = s + (k < qg ? NEGV : 0.f);
            float bw = s + (k > qg ? NEGV : 0.f);
            sfw += __expf(fw - mfw);
            sbw += __expf(bw - mbw);
        }
        #pragma unroll
        for (int m = 16; m >= 1; m >>= 1) {
            sfw += __shfl_xor(sfw, m);
            sbw += __shfl_xor(sbw, m);
        }
        float rfw = 1.f / sfw, rbw = 1.f / sbw;
        #pragma unroll
        for (int j = 0; j < 32; ++j) {
            int k = lane + (j << 5);
            float s = sv[j];
            float fw = s + (k < qg ? NEGV : 0.f);
            float bw = s + (k > qg ? NEGV : 0.f);
            sc[g][k] = __expf(fw - mfw) * rfw + __expf(bw - mbw) * rbw;
        }
    }
    __syncthreads();

    // ---- PV ----
    const int d  = t & 63;
    const int r0 = t >> 6;           // rows r0 and r0+4
    float a0 = 0.f, a1 = 0.f;
    for (int kt = 0; kt < 4; ++kt) {
        __syncthreads();
        {
            const uint4* src = reinterpret_cast<const uint4*>(Vh + (size_t)(kt * 256 + t) * 64);
            u32* dst = reinterpret_cast<u32*>(&kv[t][0]);
            #pragma unroll
            for (int i = 0; i < 8; ++i) {
                uint4 vv = src[i];
                dst[i * 4 + 0] = vv.x; dst[i * 4 + 1] = vv.y;
                dst[i * 4 + 2] = vv.z; dst[i * 4 + 3] = vv.w;
            }
        }
        __syncthreads();
        for (int kk = 0; kk < 256; ++kk) {
            float vv = b2f(kv[kk][d]);
            a0 += sc[r0][(kt << 8) + kk] * vv;
            a1 += sc[r0 + 4][(kt << 8) + kk] * vv;
        }
    }
    {
        size_t o0 = (size_t)(b * 1024 + (qt << 3) + r0) * 768 + h * 64 + d;
        size_t o1 = (size_t)(b * 1024 + (qt << 3) + r0 + 4) * 768 + h * 64 + d;
        att[o0] = f2b(a0);
        att[o1] = f2b(a1);
    }
}

// ---------------------------------------------------------------------------
// Residual + LayerNorm: 1 block per row (768 cols, 256 threads x 3).
// ---------------------------------------------------------------------------
__global__ __launch_bounds__(256) void resid_ln(
    const float* __restrict__ qin, const float* __restrict__ proj,
    const float* __restrict__ gamma, const float* __restrict__ beta,
    float* __restrict__ out)
{
    __shared__ float red[4];
    const int row = blockIdx.x;
    const int t = threadIdx.x;
    const size_t base = (size_t)row * 768;

    float x0 = qin[base + t      ] + proj[base + t      ];
    float x1 = qin[base + t + 256] + proj[base + t + 256];
    float x2 = qin[base + t + 512] + proj[base + t + 512];

    float s = x0 + x1 + x2;
    #pragma unroll
    for (int m = 32; m >= 1; m >>= 1) s += __shfl_xor(s, m);
    if ((t & 63) == 0) red[t >> 6] = s;
    __syncthreads();
    float mu = (red[0] + red[1] + red[2] + red[3]) * (1.f / 768.f);

    float d0 = x0 - mu, d1 = x1 - mu, d2 = x2 - mu;
    float vs = d0 * d0 + d1 * d1 + d2 * d2;
    #pragma unroll
    for (int m = 32; m >= 1; m >>= 1) vs += __shfl_xor(vs, m);
    __syncthreads();
    if ((t & 63) == 0) red[t >> 6] = vs;
    __syncthreads();
    float var = (red[0] + red[1] + red[2] + red[3]) * (1.f / 768.f);
    float inv = rsqrtf(var + 1e-6f);

    out[base + t      ] = d0 * inv * gamma[t      ] + beta[t      ];
    out[base + t + 256] = d1 * inv * gamma[t + 256] + beta[t + 256];
    out[base + t + 512] = d2 * inv * gamma[t + 512] + beta[t + 512];
}

// ---------------------------------------------------------------------------
extern "C" void kernel_launch(void* const* d_in, const int* in_sizes, int n_in,
                              void* d_out, int out_size, void* d_ws, size_t ws_size,
                              hipStream_t stream)
{
    const float* q     = (const float*)d_in[0];
    const float* k     = (const float*)d_in[1];
    const float* v     = (const float*)d_in[2];
    const int*   mask  = (const int*)d_in[3];
    const float* Wq    = (const float*)d_in[4];
    const float* bq    = (const float*)d_in[5];
    const float* Wk    = (const float*)d_in[6];
    const float* bk    = (const float*)d_in[7];
    const float* Wv    = (const float*)d_in[8];
    const float* bv    = (const float*)d_in[9];
    const float* Wo    = (const float*)d_in[10];
    const float* bo    = (const float*)d_in[11];
    const float* gamma = (const float*)d_in[12];
    const float* beta  = (const float*)d_in[13];

    const size_t NE = (size_t)8 * 1024 * 768;   // 6291456 elements
    u16* Qf  = (u16*)d_ws;
    u16* Kf  = Qf + NE;
    u16* Vf  = Kf + NE;
    u16* att = Vf + NE;
    float* proj = (float*)(att + NE);
    // ws bytes used: 4*NE*2 + NE*4 = 75.5 MB

    dim3 blk(256);
    dim3 gproj(12, 128);   // N/64, M/64

    gemm_bias<1,1><<<gproj, blk, 0, stream>>>(q, Wq, bq, Qf, nullptr, 8192, 768, 768);
    gemm_bias<1,1><<<gproj, blk, 0, stream>>>(k, Wk, bk, Kf, nullptr, 8192, 768, 768);
    gemm_bias<1,1><<<gproj, blk, 0, stream>>>(v, Wv, bv, Vf, nullptr, 8192, 768, 768);

    attn_kernel<<<12288, blk, 0, stream>>>(Qf, Kf, Vf, mask, att);

    gemm_bias<0,0><<<gproj, blk, 0, stream>>>(att, Wo, bo, nullptr, proj, 8192, 768, 768);

    resid_ln<<<8192, blk, 0, stream>>>(q, proj, gamma, beta, (float*)d_out);
}

// Round 3
// 334.698 us; speedup vs baseline: 5.6355x; 5.6355x over previous
//
#include <hip/hip_runtime.h>
#include <hip/hip_bf16.h>

typedef unsigned short u16;
typedef unsigned int u32;
typedef __attribute__((ext_vector_type(8))) short short8v;
typedef __attribute__((ext_vector_type(4))) float f32x4;

#define MFMA16(a,b,c) __builtin_amdgcn_mfma_f32_16x16x32_bf16(a,b,c,0,0,0)
#define NEGV -1e9f

__device__ __forceinline__ float b2f(u16 u){ return __uint_as_float(((u32)u)<<16); }
__device__ __forceinline__ u16 f2b(float f){
  u32 u = __float_as_uint(f);
  return (u16)((u + 0x7FFFu + ((u>>16)&1u)) >> 16);
}
__device__ __forceinline__ u32 pk2(float a, float b){
  return (u32)f2b(a) | ((u32)f2b(b) << 16);
}

// ---------------------------------------------------------------------------
// MFMA GEMM: C = A(8192x768) @ W(768x768) + bias.
// Tile 128x64, 4 waves (2x2), K-step 32, mfma_f32_16x16x32_bf16.
// ABF16: A is bf16 (u16) else fp32 (converted in staging). W always fp32.
// OMODE 0: fp32 row-major; 1: bf16 head-split [bh][l][64];
//       2: bf16 head-split TRANSPOSED [bh][d][1024]  (for V).
// ---------------------------------------------------------------------------
template<int ABF16, int OMODE>
__global__ __launch_bounds__(256) void gemm_mfma(
    const void* __restrict__ Av, const float* __restrict__ W,
    const float* __restrict__ bias, float* __restrict__ outF,
    u16* __restrict__ outB)
{
  constexpr int K = 768, N = 768;
  __shared__ u16 Al[128*40];   // [row][k] pad 40 u16 (80B stride: 2-way free)
  __shared__ u16 Bl[64*40];    // [n][k] transposed W tile
  const int t = threadIdx.x;
  const int lane = t & 63, wid = t >> 6;
  const int l15 = lane & 15, lg = lane >> 4;
  const int wm = wid >> 1, wn = wid & 1;
  const int n0 = blockIdx.x * 64, m0 = blockIdx.y * 128;

  f32x4 acc[4][2];
  #pragma unroll
  for (int mi = 0; mi < 4; ++mi)
    #pragma unroll
    for (int ni = 0; ni < 2; ++ni)
      acc[mi][ni] = (f32x4){0.f,0.f,0.f,0.f};

  const int arow = t >> 1, aseg = (t & 1) * 16;
  const int brow = t >> 3, bseg = (t & 7) * 8;

  for (int k0 = 0; k0 < K; k0 += 32) {
    __syncthreads();
    if (ABF16) {
      const u16* A = (const u16*)Av + (size_t)(m0 + arow) * K + k0 + aseg;
      uint4 a0 = *(const uint4*)(A);
      uint4 a1 = *(const uint4*)(A + 8);
      *(uint4*)&Al[arow*40 + aseg]     = a0;
      *(uint4*)&Al[arow*40 + aseg + 8] = a1;
    } else {
      const float* A = (const float*)Av + (size_t)(m0 + arow) * K + k0 + aseg;
      float4 f0 = ((const float4*)A)[0];
      float4 f1 = ((const float4*)A)[1];
      float4 f2 = ((const float4*)A)[2];
      float4 f3 = ((const float4*)A)[3];
      uint4 o0 = { pk2(f0.x,f0.y), pk2(f0.z,f0.w), pk2(f1.x,f1.y), pk2(f1.z,f1.w) };
      uint4 o1 = { pk2(f2.x,f2.y), pk2(f2.z,f2.w), pk2(f3.x,f3.y), pk2(f3.z,f3.w) };
      *(uint4*)&Al[arow*40 + aseg]     = o0;
      *(uint4*)&Al[arow*40 + aseg + 8] = o1;
    }
    {
      const float* Wp = W + (size_t)(k0 + brow) * N + n0 + bseg;
      float4 w0 = ((const float4*)Wp)[0];
      float4 w1 = ((const float4*)Wp)[1];
      Bl[(bseg+0)*40 + brow] = f2b(w0.x);
      Bl[(bseg+1)*40 + brow] = f2b(w0.y);
      Bl[(bseg+2)*40 + brow] = f2b(w0.z);
      Bl[(bseg+3)*40 + brow] = f2b(w0.w);
      Bl[(bseg+4)*40 + brow] = f2b(w1.x);
      Bl[(bseg+5)*40 + brow] = f2b(w1.y);
      Bl[(bseg+6)*40 + brow] = f2b(w1.z);
      Bl[(bseg+7)*40 + brow] = f2b(w1.w);
    }
    __syncthreads();
    short8v af[4], bfv[2];
    #pragma unroll
    for (int mi = 0; mi < 4; ++mi)
      af[mi] = *(const short8v*)&Al[(wm*64 + mi*16 + l15)*40 + lg*8];
    #pragma unroll
    for (int ni = 0; ni < 2; ++ni)
      bfv[ni] = *(const short8v*)&Bl[(wn*32 + ni*16 + l15)*40 + lg*8];
    #pragma unroll
    for (int mi = 0; mi < 4; ++mi)
      #pragma unroll
      for (int ni = 0; ni < 2; ++ni)
        acc[mi][ni] = MFMA16(af[mi], bfv[ni], acc[mi][ni]);
  }

  #pragma unroll
  for (int mi = 0; mi < 4; ++mi)
  #pragma unroll
  for (int ni = 0; ni < 2; ++ni) {
    const int col  = n0 + wn*32 + ni*16 + l15;
    const int row0 = m0 + wm*64 + mi*16 + lg*4;
    const float bv = bias[col];
    if (OMODE == 0) {
      #pragma unroll
      for (int r = 0; r < 4; ++r)
        outF[(size_t)(row0 + r) * N + col] = acc[mi][ni][r] + bv;
    } else if (OMODE == 1) {
      const int h = col >> 6, d = col & 63;
      #pragma unroll
      for (int r = 0; r < 4; ++r) {
        const int row = row0 + r;
        const int bb = row >> 10, l = row & 1023;
        outB[(((size_t)(bb*12 + h))*1024 + l)*64 + d] = f2b(acc[mi][ni][r] + bv);
      }
    } else {
      const int h = col >> 6, d = col & 63;
      const int bb = row0 >> 10, l0 = row0 & 1023;
      ushort4 pk;
      pk.x = f2b(acc[mi][ni][0] + bv);
      pk.y = f2b(acc[mi][ni][1] + bv);
      pk.z = f2b(acc[mi][ni][2] + bv);
      pk.w = f2b(acc[mi][ni][3] + bv);
      *(ushort4*)(outB + (((size_t)(bb*12 + h))*64 + d)*1024 + l0) = pk;
    }
  }
}

// ---------------------------------------------------------------------------
// Fused MFMA attention. Block = (bh, 64 q-rows); wave = 16 q-rows.
// All 16 K-tiles processed for BOTH fw and bw sides (reproduces the
// reference's fp32 "-1e9 add" arithmetic exactly, incl. degenerate rows
// where s-1e9 rounds to exactly -1e9).
// Q in regs; K row-major + V transposed [d][k] in LDS (+8 u16 pad).
// ---------------------------------------------------------------------------
__global__ __launch_bounds__(256) void attn_mfma(
    const u16* __restrict__ Qf, const u16* __restrict__ Kf,
    const u16* __restrict__ Vt, const int* __restrict__ mask,
    u16* __restrict__ att)
{
  __shared__ u16 Kl[64*72];
  __shared__ u16 Vl[64*72];
  __shared__ u16 Pl[4][16*72];
  __shared__ int pml[64];

  const int t = threadIdx.x;
  const int lane = t & 63, wid = t >> 6;
  const int l15 = lane & 15, lg = lane >> 4;
  const int blk = blockIdx.x;
  const int qt = blk & 15, bh = blk >> 4;
  const int b = bh / 12, h = bh - b*12;
  const int rowg0 = qt*64 + wid*16;

  short8v qa0, qa1;
  {
    const u16* Qp = Qf + ((size_t)bh*1024 + rowg0 + l15)*64 + lg*8;
    qa0 = *(const short8v*)(Qp);
    qa1 = *(const short8v*)(Qp + 32);
  }

  f32x4 accf[4], accb[4];
  float Mf[4], Lf[4], Mb[4], Lb[4];
  #pragma unroll
  for (int i = 0; i < 4; ++i) {
    accf[i] = (f32x4){0,0,0,0}; accb[i] = (f32x4){0,0,0,0};
    Mf[i] = -3.0e38f; Mb[i] = -3.0e38f; Lf[i] = 0.f; Lb[i] = 0.f;
  }

  const int sr = t >> 2, scq = (t & 3) * 16;

  for (int kt = 0; kt < 16; ++kt) {
    __syncthreads();
    {
      const u16* ks = Kf + ((size_t)bh*1024 + kt*64 + sr)*64 + scq;
      uint4 k0 = *(const uint4*)(ks);
      uint4 k1 = *(const uint4*)(ks + 8);
      *(uint4*)&Kl[sr*72 + scq]     = k0;
      *(uint4*)&Kl[sr*72 + scq + 8] = k1;
      const u16* vs = Vt + ((size_t)bh*64 + sr)*1024 + kt*64 + scq;
      uint4 v0 = *(const uint4*)(vs);
      uint4 v1 = *(const uint4*)(vs + 8);
      *(uint4*)&Vl[sr*72 + scq]     = v0;
      *(uint4*)&Vl[sr*72 + scq + 8] = v1;
      if (t < 64) pml[t] = mask[b*1024 + kt*64 + t];
    }
    __syncthreads();

    // S = Q K^T (16x64), scale + padding mask (replace semantics)
    f32x4 sv[4];
    #pragma unroll
    for (int ni = 0; ni < 4; ++ni) {
      const u16* kr = &Kl[(ni*16 + l15)*72 + lg*8];
      short8v b0 = *(const short8v*)(kr);
      short8v b1 = *(const short8v*)(kr + 32);
      f32x4 z = (f32x4){0,0,0,0};
      z = MFMA16(qa0, b0, z);
      z = MFMA16(qa1, b1, z);
      const int pm = pml[ni*16 + l15];
      #pragma unroll
      for (int r = 0; r < 4; ++r)
        z[r] = pm ? NEGV : z[r]*0.125f;
      sv[ni] = z;
    }

    const int colg0 = kt*64;
    #pragma unroll
    for (int side = 0; side < 2; ++side) {
      float* M = side ? Mb : Mf;
      float* L = side ? Lb : Lf;
      f32x4* acc = side ? accb : accf;

      float x[4][4];
      float mt[4] = {-3.0e38f,-3.0e38f,-3.0e38f,-3.0e38f};
      #pragma unroll
      for (int ni = 0; ni < 4; ++ni) {
        const int colg = colg0 + ni*16 + l15;
        #pragma unroll
        for (int r = 0; r < 4; ++r) {
          const int rowg = rowg0 + lg*4 + r;
          const bool msk = side ? (colg > rowg) : (colg < rowg);
          const float xx = sv[ni][r] + (msk ? NEGV : 0.f);
          x[ni][r] = xx;
          mt[r] = fmaxf(mt[r], xx);
        }
      }
      #pragma unroll
      for (int s = 1; s <= 8; s <<= 1)
        #pragma unroll
        for (int r = 0; r < 4; ++r)
          mt[r] = fmaxf(mt[r], __shfl_xor(mt[r], s));

      float cf[4], ps[4];
      #pragma unroll
      for (int r = 0; r < 4; ++r) {
        const float Mn = fmaxf(M[r], mt[r]);
        cf[r] = __expf(M[r] - Mn);
        M[r] = Mn;
        ps[r] = 0.f;
      }
      #pragma unroll
      for (int ni = 0; ni < 4; ++ni)
        #pragma unroll
        for (int r = 0; r < 4; ++r) {
          const float p = __expf(x[ni][r] - M[r]);
          x[ni][r] = p;
          ps[r] += p;
        }
      #pragma unroll
      for (int s = 1; s <= 8; s <<= 1)
        #pragma unroll
        for (int r = 0; r < 4; ++r)
          ps[r] += __shfl_xor(ps[r], s);
      #pragma unroll
      for (int r = 0; r < 4; ++r)
        L[r] = L[r]*cf[r] + ps[r];
      #pragma unroll
      for (int fd = 0; fd < 4; ++fd)
        #pragma unroll
        for (int r = 0; r < 4; ++r)
          acc[fd][r] *= cf[r];

      // P -> LDS (wave-private region; wave-lockstep, no barrier needed)
      u16* Pw = &Pl[wid][0];
      #pragma unroll
      for (int ni = 0; ni < 4; ++ni)
        #pragma unroll
        for (int r = 0; r < 4; ++r)
          Pw[(lg*4 + r)*72 + ni*16 + l15] = f2b(x[ni][r]);

      short8v pa0 = *(const short8v*)(Pw + l15*72 + lg*8);
      short8v pa1 = *(const short8v*)(Pw + l15*72 + lg*8 + 32);
      #pragma unroll
      for (int fd = 0; fd < 4; ++fd) {
        const u16* vr = &Vl[(fd*16 + l15)*72 + lg*8];
        short8v v0 = *(const short8v*)(vr);
        short8v v1 = *(const short8v*)(vr + 32);
        acc[fd] = MFMA16(pa0, v0, acc[fd]);
        acc[fd] = MFMA16(pa1, v1, acc[fd]);
      }
    }
  }

  float rf[4], rb[4];
  #pragma unroll
  for (int r = 0; r < 4; ++r) { rf[r] = 1.f/Lf[r]; rb[r] = 1.f/Lb[r]; }
  #pragma unroll
  for (int fd = 0; fd < 4; ++fd)
    #pragma unroll
    for (int r = 0; r < 4; ++r) {
      const float val = accf[fd][r]*rf[r] + accb[fd][r]*rb[r];
      att[((size_t)(b*1024 + rowg0 + lg*4 + r))*768 + h*64 + fd*16 + l15] = f2b(val);
    }
}

// ---------------------------------------------------------------------------
// Residual + LayerNorm: 1 block per row (768 cols, 256 threads x 3).
// ---------------------------------------------------------------------------
__global__ __launch_bounds__(256) void resid_ln(
    const float* __restrict__ qin, const float* __restrict__ proj,
    const float* __restrict__ gamma, const float* __restrict__ beta,
    float* __restrict__ out)
{
    __shared__ float red[4];
    const int row = blockIdx.x;
    const int t = threadIdx.x;
    const size_t base = (size_t)row * 768;

    float x0 = qin[base + t      ] + proj[base + t      ];
    float x1 = qin[base + t + 256] + proj[base + t + 256];
    float x2 = qin[base + t + 512] + proj[base + t + 512];

    float s = x0 + x1 + x2;
    #pragma unroll
    for (int m = 32; m >= 1; m >>= 1) s += __shfl_xor(s, m);
    if ((t & 63) == 0) red[t >> 6] = s;
    __syncthreads();
    float mu = (red[0] + red[1] + red[2] + red[3]) * (1.f / 768.f);

    float d0 = x0 - mu, d1 = x1 - mu, d2 = x2 - mu;
    float vs = d0 * d0 + d1 * d1 + d2 * d2;
    #pragma unroll
    for (int m = 32; m >= 1; m >>= 1) vs += __shfl_xor(vs, m);
    __syncthreads();
    if ((t & 63) == 0) red[t >> 6] = vs;
    __syncthreads();
    float var = (red[0] + red[1] + red[2] + red[3]) * (1.f / 768.f);
    float inv = rsqrtf(var + 1e-6f);

    out[base + t      ] = d0 * inv * gamma[t      ] + beta[t      ];
    out[base + t + 256] = d1 * inv * gamma[t + 256] + beta[t + 256];
    out[base + t + 512] = d2 * inv * gamma[t + 512] + beta[t + 512];
}

// ---------------------------------------------------------------------------
extern "C" void kernel_launch(void* const* d_in, const int* in_sizes, int n_in,
                              void* d_out, int out_size, void* d_ws, size_t ws_size,
                              hipStream_t stream)
{
    const float* q     = (const float*)d_in[0];
    const float* k     = (const float*)d_in[1];
    const float* v     = (const float*)d_in[2];
    const int*   mask  = (const int*)d_in[3];
    const float* Wq    = (const float*)d_in[4];
    const float* bq    = (const float*)d_in[5];
    const float* Wk    = (const float*)d_in[6];
    const float* bk    = (const float*)d_in[7];
    const float* Wv    = (const float*)d_in[8];
    const float* bv    = (const float*)d_in[9];
    const float* Wo    = (const float*)d_in[10];
    const float* bo    = (const float*)d_in[11];
    const float* gamma = (const float*)d_in[12];
    const float* beta  = (const float*)d_in[13];

    const size_t NE = (size_t)8 * 1024 * 768;
    u16* Qf  = (u16*)d_ws;              // [bh][l][64]
    u16* Kf  = Qf + NE;                 // [bh][l][64]
    u16* Vt  = Kf + NE;                 // [bh][d][1024]
    u16* att = Vt + NE;                 // [b*l][768]
    float* proj = (float*)(att + NE);   // [b*l][768] fp32
    // ws bytes: 4*NE*2 + NE*4 = 75.5 MB

    dim3 blk(256);
    dim3 gg(12, 64);

    gemm_mfma<0,1><<<gg, blk, 0, stream>>>(q, Wq, bq, nullptr, Qf);
    gemm_mfma<0,1><<<gg, blk, 0, stream>>>(k, Wk, bk, nullptr, Kf);
    gemm_mfma<0,2><<<gg, blk, 0, stream>>>(v, Wv, bv, nullptr, Vt);

    attn_mfma<<<1536, blk, 0, stream>>>(Qf, Kf, Vt, mask, att);

    gemm_mfma<1,0><<<gg, blk, 0, stream>>>(att, Wo, bo, proj, nullptr);

    resid_ln<<<8192, blk, 0, stream>>>(q, proj, gamma, beta, (float*)d_out);
}